// Round 6
// baseline (433.252 us; speedup 1.0000x reference)
//
#include <hip/hip_runtime.h>
#include <hip/hip_bf16.h>

// MLA absorbed causal attention, MI355X round 11:
//  flash v9: QK pair k-split. Unified model: kernel is LDS-read-byte-bound
//  (~85 B/cyc effective): QK's 8x redundant K-tile read (256 KB/round/CU) is
//  the dominant term. Now each pair wave reads only its lat-half (16 b128)
//  and computes PARTIAL S for BOTH pair query sets (each A-frag feeds 2
//  MFMAs; 32 MFMAs/wave unchanged; Q regs 8+8 frags = 64, unchanged).
//  Partials exchanged via Sx LDS (+18 KB) + one lgkm-only barrier, summed;
//  mask/softmax/P/PV/epilogue and v8 counted-vmcnt scheme unchanged.
// fp32 I/O. d_out = [ y (2*2048*1024) | c_kv (2*2048*512) ] fp32.

using bf16 = __hip_bfloat16;
using u32  = unsigned int;
using short8 = __attribute__((ext_vector_type(8))) short;   // 8 bf16 (4 VGPRs)
using f4     = __attribute__((ext_vector_type(4))) float;   // 16x16 accumulator
using f16v   = __attribute__((ext_vector_type(16))) float;  // 32x32 accumulator

static constexpr int kB  = 2;
static constexpr int kT  = 2048;
static constexpr int kC  = 1024;
static constexpr int kNH = 16;
static constexpr int kL  = 512;

__device__ inline u32 f2bf2(float a, float b) {
  bf16 ha = __float2bfloat16(a), hb = __float2bfloat16(b);
  unsigned short ua, ub;
  __builtin_memcpy(&ua, &ha, 2);
  __builtin_memcpy(&ub, &hb, 2);
  return (u32)ua | ((u32)ub << 16);
}
__device__ inline unsigned short f2bf(float x) {
  bf16 h = __float2bfloat16(x);
  unsigned short u; __builtin_memcpy(&u, &h, 2);
  return u;
}
__device__ inline short8 frag_ld(const void* p) {   // 16B aligned -> ds/global b128
  short8 r; __builtin_memcpy(&r, p, 16); return r;
}
// async global->LDS DMA, 16 B/lane. dest = wave-uniform base + lane*16.
__device__ inline void g2lds16(const bf16* g, bf16* l) {
  __builtin_amdgcn_global_load_lds(
      (const __attribute__((address_space(1))) u32*)g,
      (__attribute__((address_space(3))) u32*)l, 16, 0, 0);
}

// ---- fused flat casts: x, W_dq, W_uq, W_dkv, W_o -> bf16 ----
__global__ __launch_bounds__(256)
void casts_all(const float* __restrict__ x,   const float* __restrict__ wdq,
               const float* __restrict__ wuq, const float* __restrict__ wdkv,
               const float* __restrict__ wo,
               bf16* __restrict__ xb,   bf16* __restrict__ wdqb,
               bf16* __restrict__ wuqb, bf16* __restrict__ wdkvb,
               bf16* __restrict__ wob)
{
  long i = (long)(blockIdx.x * 256 + threadIdx.x) * 4;
  const float* s; bf16* d; long off;
  if      (i < 4194304) { s = x;    d = xb;    off = i; }
  else if (i < 4718592) { s = wdq;  d = wdqb;  off = i - 4194304; }
  else if (i < 5242880) { s = wuq;  d = wuqb;  off = i - 4718592; }
  else if (i < 5767168) { s = wdkv; d = wdkvb; off = i - 5242880; }
  else                  { s = wo;   d = wob;   off = i - 5767168; }
  float4 v = *(const float4*)(s + off);
  *(uint2*)((u32*)d + off / 2) = make_uint2(f2bf2(v.x, v.y), f2bf2(v.z, v.w));
}

// bf16 -> fp32 upcast (final c_kv output write). n multiple of 1024.
__global__ __launch_bounds__(256)
void upcast_kernel(const bf16* __restrict__ src, float* __restrict__ dst, int n)
{
  int i = (blockIdx.x * 256 + threadIdx.x) * 4;
  if (i < n) {
    uint2 v = *(const uint2*)((const u32*)src + i / 2);
    float4 o;
    o.x = __uint_as_float(v.x << 16);
    o.y = __uint_as_float(v.x & 0xffff0000u);
    o.z = __uint_as_float(v.y << 16);
    o.w = __uint_as_float(v.y & 0xffff0000u);
    *(float4*)(dst + i) = o;
  }
}

// ---- fused transpose-casts: z selects (src,dst,R,C); guards for shape ----
__global__ __launch_bounds__(256)
void tcasts_all(const float* __restrict__ wuq, const float* __restrict__ wuk,
                const float* __restrict__ wuv, const float* __restrict__ wdq,
                bf16* __restrict__ uqT, bf16* __restrict__ ukT,
                bf16* __restrict__ uvT, bf16* __restrict__ dqT)
{
  const int z = blockIdx.z;
  const float* src = z == 0 ? wuq : z == 1 ? wuk : z == 2 ? wuv : wdq;
  bf16* dst        = z == 0 ? uqT : z == 1 ? ukT : z == 2 ? uvT : dqT;
  const int R = (z == 3) ? 512 : 1024, C = (z == 3) ? 1024 : 512;
  const int r0 = blockIdx.x * 32, c0 = blockIdx.y * 32;
  if (r0 >= R || c0 >= C) return;
  __shared__ float s[32][33];
  const int x = threadIdx.x & 31, y = threadIdx.x >> 5;   // y: 0..7
#pragma unroll
  for (int i = 0; i < 4; ++i)
    s[y*4 + i][x] = src[(long)(r0 + y*4 + i) * C + c0 + x];
  __syncthreads();
  unsigned short* dp = (unsigned short*)dst;
#pragma unroll
  for (int i = 0; i < 4; ++i)
    dp[(long)(c0 + y*4 + i) * R + r0 + x] = f2bf(s[x][y*4 + i]);
}

// ckv [b][2048][512] -> ckvT [b][512][2048] (bf16).
__global__ __launch_bounds__(256)
void transpose_ckv(const bf16* __restrict__ src, bf16* __restrict__ dst)
{
  __shared__ unsigned short s[32][33];
  const int b = blockIdx.z, t0 = blockIdx.x * 32, l0 = blockIdx.y * 32;
  const int x = threadIdx.x & 31, y = threadIdx.x >> 5;
  const unsigned short* sp = (const unsigned short*)(src + (long)b * kT * kL);
  unsigned short* dp = (unsigned short*)(dst + (long)b * kL * kT);
#pragma unroll
  for (int i = 0; i < 4; ++i)
    s[y*4 + i][x] = sp[(long)(t0 + y*4 + i) * kL + l0 + x];
  __syncthreads();
#pragma unroll
  for (int i = 0; i < 4; ++i)
    dp[(long)(l0 + y*4 + i) * kT + t0 + x] = s[x][y*4 + i];
}

// ---------------------------------------------------------------------------
// NT MFMA GEMM (round-3 proven): C[m][n] = alpha * sum_k A[m][k] * B[n][k].
// ---------------------------------------------------------------------------
template<typename TCe>
__global__ __launch_bounds__(256)
void mm_nt(const bf16* __restrict__ A, int lda, long aHi, long aLo,
           const bf16* __restrict__ Bm, int ldb, long bHi, long bLo,
           TCe* __restrict__ Cm, int ldc, long cHi, long cLo,
           int K, float alpha)
{
  const int z = blockIdx.z;
  A  += (long)(z >> 4) * aHi + (long)(z & 15) * aLo;
  Bm += (long)(z >> 4) * bHi + (long)(z & 15) * bLo;
  Cm += (long)(z >> 4) * cHi + (long)(z & 15) * cLo;

  __shared__ __align__(16) bf16 As[64][72];
  __shared__ __align__(16) bf16 Bs[64][72];

  const int tid = threadIdx.x;
  const int w = tid >> 6, lane = tid & 63;
  const int quad = lane >> 4, lp = lane & 15;
  const int m0 = blockIdx.x * 64, n0 = blockIdx.y * 64;
  const int row = tid >> 2, cseg = (tid & 3) * 16;

  f4 acc[4];
#pragma unroll
  for (int i = 0; i < 4; ++i) acc[i] = f4{0.f, 0.f, 0.f, 0.f};

  for (int k0 = 0; k0 < K; k0 += 64) {
    const bf16* ag = A  + (long)(m0 + row) * lda + k0 + cseg;
    const bf16* bg = Bm + (long)(n0 + row) * ldb + k0 + cseg;
    uint4 a0 = *(const uint4*)ag, a1 = *(const uint4*)(ag + 8);
    uint4 b0 = *(const uint4*)bg, b1 = *(const uint4*)(bg + 8);
    __syncthreads();
    *(uint4*)&As[row][cseg] = a0; *(uint4*)&As[row][cseg + 8] = a1;
    *(uint4*)&Bs[row][cseg] = b0; *(uint4*)&Bs[row][cseg + 8] = b1;
    __syncthreads();

    short8 af0 = frag_ld(&As[w*16 + lp][quad * 8]);
    short8 af1 = frag_ld(&As[w*16 + lp][32 + quad * 8]);
#pragma unroll
    for (int nb = 0; nb < 4; ++nb) {
      short8 bf0 = frag_ld(&Bs[nb*16 + lp][quad * 8]);
      short8 bf1 = frag_ld(&Bs[nb*16 + lp][32 + quad * 8]);
      acc[nb] = __builtin_amdgcn_mfma_f32_16x16x32_bf16(af0, bf0, acc[nb], 0, 0, 0);
      acc[nb] = __builtin_amdgcn_mfma_f32_16x16x32_bf16(af1, bf1, acc[nb], 0, 0, 0);
    }
  }
#pragma unroll
  for (int nb = 0; nb < 4; ++nb)
#pragma unroll
    for (int r = 0; r < 4; ++r) {
      float v = alpha * acc[nb][r];
      long off = (long)(m0 + w*16 + quad*4 + r) * ldc + n0 + nb*16 + lp;
      if constexpr (__is_same(TCe, float)) Cm[off] = v;
      else ((unsigned short*)Cm)[off] = f2bf(v);
    }
}

// ---------------------------------------------------------------------------
// MFMA flash attention v9: 512-thread WG (8 waves = 4 pairs), double-buffered
// DMA staging, counted-vmcnt raw barriers (v8), QK pair k-split (new).
// Wave w: kh = w&1 = its lat-half. QK: reads Ks rows {lp, 16+lp} x lat-half
// kh only (16 b128), computes partial S for BOTH pair query sets (4 MFMA
// chains, 32 MFMAs). Partials cross the pair via Sx (+lgkm barrier bX), sum,
// then mask/softmax/P/PV identical to v8.
// Round: issue Ks(t+1),KsT(t+1) -> QK-partials -> Sx write
//   -> bX {lgkm0; s_barrier}            (Sx visible; DMAs ride through)
//   -> Sx read + sum -> mask -> softmax -> P/alpha write
//   -> bA {vmcnt(8) lgkm0; s_barrier}   (drains KsT(t) only)
//   -> rescale + PV(32x32x16)
//   -> bB {vmcnt(4) lgkm0; s_barrier}   (drains Ks(t+1) only).
// Ks[32][512]: phys 16B-block v of row r holds global block v ^ (r&7).
// KsT[512][32]: phys seg s of row rr holds global seg s ^ ((rr>>1)&3).
// Sx[pair][tph][16 q][36 f32]: wave w writes partner-set partials to
// tph = 1-kh, reads own-set partials from tph = kh (written by its mate).
// ---------------------------------------------------------------------------
__global__ __launch_bounds__(512, 2)
void flash_mfma(bf16* __restrict__ qlat, const bf16* __restrict__ ckv,
                const bf16* __restrict__ ckvT)
{
  const int jj = blockIdx.x, h = blockIdx.y, b = blockIdx.z;
  const int tid = threadIdx.x;
  const int w = tid >> 6, lane = tid & 63;
  const int quad = lane >> 4, lp = lane & 15;
  const int hi = lane >> 5, la = lane & 31;
  const int p = w >> 1, ph = w & 1;         // pair index, half index
  const int kh = ph;                        // QK lat-half owned by this wave
  const int L0 = ph * 256;                  // PV lat-half base

  __shared__ __align__(16) bf16 Ks[2][32 * 512];           // 64 KB
  __shared__ __align__(16) bf16 KsT[2][512 * 32];          // 64 KB
  __shared__ __align__(16) unsigned short Pp[4][32][40];   // 10 KB pair P
  __shared__ float Axf[4][32];                             // pair alpha / l
  __shared__ __align__(16) float Sx[4][2][16][36];         // 18 KB partials

  const bf16* ckb = ckv  + (long)b * kT * kL;
  const bf16* ckt = ckvT + (long)b * kL * kT;

  // per-lane staging constants (element units)
  int ksOff[4], ktRow[4];
#pragma unroll
  for (int i = 0; i < 4; ++i) {
    int r = w * 4 + i;                              // Ks row 0..31
    ksOff[i] = r * 512 + ((lane & ~7) | ((lane ^ r) & 7)) * 8;
    ktRow[i] = (w * 4 + i) * 16 + (lane >> 2);      // KsT row 0..511
  }
  const int ktSeg = ((lane & 3) ^ ((lane >> 3) & 3)) * 8;   // lane-only

  // QK A-frag swizzle decomposition (v6, proven), now over lat-half kh
  const int cA    = lp & 7;
  const int laneA = lp * 512 + (quad ^ (cA & 3)) * 8;
  const int pOffE = (cA >> 2) * 32;
  const int pOffO = 32 - pOffE;

  // PV A-frag lane constants: read KsT[L0 + lb*32 + la][seg], seg swizzled
  const int cs = (la >> 1) & 3;
  const int pvBase = (L0 + la) * 32;                // + lb*1024 + offk
  const int offk0 = ((0 + hi) ^ cs) * 8;            // kstep 0 (keys 0-15)
  const int offk1 = ((2 + hi) ^ cs) * 8;            // kstep 1 (keys 16-31)

  for (int half = 0; half < 2; ++half) {
    const int stripe = half ? (15 - jj) : jj;
    const int qb = 8 * stripe + w, q0 = qb * 16;           // wave's 16 queries
    const int qM0 = (8 * stripe + (w ^ 1)) * 16;           // mate's 16 queries
    const int q0p = stripe * 128 + p * 32;                 // pair's 32 queries
    bf16* qbase  = qlat + (((long)(b * kNH + h)) * kT + q0) * kL;
    bf16* qbaseM = qlat + (((long)(b * kNH + h)) * kT + qM0) * kL;
    bf16* qbaseP = qlat + (((long)(b * kNH + h)) * kT + q0p) * kL;

    // persistent Q fragments (B-operand form), lat-half kh only:
    // qfo = own queries, qfp = mate's queries. 8+8 frags = 64 VGPRs.
    short8 qfo[8], qfp[8];
#pragma unroll
    for (int lb = 0; lb < 8; ++lb) {
      qfo[lb] = frag_ld(qbase  + (long)lp * kL + kh*256 + lb * 32 + quad * 8);
      qfp[lb] = frag_ld(qbaseM + (long)lp * kL + kh*256 + lb * 32 + quad * 8);
    }

    f16v O32[8];
#pragma unroll
    for (int ct = 0; ct < 8; ++ct)
#pragma unroll
      for (int j = 0; j < 16; ++j) O32[ct][j] = 0.f;
    float m_r = -3e38f, l_r = 0.f;

    const int tmax = qb >> 1;                // pair-uniform
    const int nt = 4 * stripe + 4;

    // prologue: stage tile 0 into buffer 0 (Ks first, then KsT)
    {
      const bf16* kbase = ckb;                 // t = 0
#pragma unroll
      for (int i = 0; i < 4; ++i)
        g2lds16(kbase + ksOff[i], &Ks[0][(w * 4 + i) * 512]);
      const bf16* tbase = ckt + ktSeg;
#pragma unroll
      for (int i = 0; i < 4; ++i)
        g2lds16(tbase + (long)ktRow[i] * kT, &KsT[0][(w * 4 + i) * 512]);
    }
    // drain qf + Ks(0); KsT(0) (4 newest) stays in flight until round-0 A
    asm volatile("s_waitcnt vmcnt(4)" ::: "memory");
    __builtin_amdgcn_s_barrier();
    __builtin_amdgcn_sched_barrier(0);

    for (int t = 0; t < nt; ++t) {
      const int bf = t & 1;
      const bool pre = (t + 1 < nt);
      if (pre) {                        // stage t+1: Ks first, then KsT
        const bf16* kbase = ckb + (long)(t + 1) * 32 * kL;
#pragma unroll
        for (int i = 0; i < 4; ++i)
          g2lds16(kbase + ksOff[i], &Ks[bf ^ 1][(w * 4 + i) * 512]);
        const bf16* tbase = ckt + (long)(t + 1) * 32 + ktSeg;
#pragma unroll
        for (int i = 0; i < 4; ++i)
          g2lds16(tbase + (long)ktRow[i] * kT, &KsT[bf ^ 1][(w * 4 + i) * 512]);
      }

      f4 s0 = f4{0.f,0.f,0.f,0.f}, s1 = f4{0.f,0.f,0.f,0.f};
      if (t <= tmax) {
        // ---- partial S^T over lat-half kh for BOTH pair query sets ----
        // 16 b128 reads, 32 MFMAs (each A-frag feeds own + mate chains).
        const bf16* pe = Ks[bf] + kh*256 + laneA + pOffE;   // even lb
        const bf16* po = Ks[bf] + kh*256 + laneA + pOffO;   // odd lb
        f4 s0p = f4{0.f,0.f,0.f,0.f}, s1p = f4{0.f,0.f,0.f,0.f};
#pragma unroll
        for (int lb2 = 0; lb2 < 4; ++lb2) {
          short8 a0 = frag_ld(pe + lb2 * 64);
          short8 a1 = frag_ld(pe + lb2 * 64 + 16 * 512);
          s0  = __builtin_amdgcn_mfma_f32_16x16x32_bf16(a0, qfo[2*lb2], s0,  0, 0, 0);
          s0p = __builtin_amdgcn_mfma_f32_16x16x32_bf16(a0, qfp[2*lb2], s0p, 0, 0, 0);
          s1  = __builtin_amdgcn_mfma_f32_16x16x32_bf16(a1, qfo[2*lb2], s1,  0, 0, 0);
          s1p = __builtin_amdgcn_mfma_f32_16x16x32_bf16(a1, qfp[2*lb2], s1p, 0, 0, 0);
          short8 a2 = frag_ld(po + lb2 * 64);
          short8 a3 = frag_ld(po + lb2 * 64 + 16 * 512);
          s0  = __builtin_amdgcn_mfma_f32_16x16x32_bf16(a2, qfo[2*lb2+1], s0,  0, 0, 0);
          s0p = __builtin_amdgcn_mfma_f32_16x16x32_bf16(a2, qfp[2*lb2+1], s0p, 0, 0, 0);
          s1  = __builtin_amdgcn_mfma_f32_16x16x32_bf16(a3, qfo[2*lb2+1], s1,  0, 0, 0);
          s1p = __builtin_amdgcn_mfma_f32_16x16x32_bf16(a3, qfp[2*lb2+1], s1p, 0, 0, 0);
        }
        // write partner-set partials to Sx[p][1-kh]
        *(float4*)&Sx[p][1 - kh][lp][quad * 4] =
            float4{s0p[0], s0p[1], s0p[2], s0p[3]};
        *(float4*)&Sx[p][1 - kh][lp][16 + quad * 4] =
            float4{s1p[0], s1p[1], s1p[2], s1p[3]};
      }

      // ---- bX: partials pair-visible (no vmcnt: DMAs ride through) ----
      asm volatile("s_waitcnt lgkmcnt(0)" ::: "memory");
      __builtin_amdgcn_s_barrier();
      __builtin_amdgcn_sched_barrier(0);

      if (t <= tmax) {
        // ---- read own-set other-half partials (written by mate), sum ----
        float4 r0 = *(const float4*)&Sx[p][kh][lp][quad * 4];
        float4 r1 = *(const float4*)&Sx[p][kh][lp][16 + quad * 4];
        s0[0] += r0.x; s0[1] += r0.y; s0[2] += r0.z; s0[3] += r0.w;
        s1[0] += r1.x; s1[1] += r1.y; s1[2] += r1.z; s1[3] += r1.w;

        // ---- causal mask: key = t*32 + chain*16 + quad*4 + r, q = q0+lp ----
        if (t == tmax) {
          const int k0 = t * 32, q = q0 + lp;
#pragma unroll
          for (int r = 0; r < 4; ++r) {
            if (k0 + quad * 4 + r > q)      s0[r] = -3e38f;
            if (k0 + 16 + quad * 4 + r > q) s1[r] = -3e38f;
          }
        }

        // ---- online softmax, defer-max (rescale deferred to pair phase) ----
        float tm = fmaxf(fmaxf(fmaxf(s0[0], s0[1]), fmaxf(s0[2], s0[3])),
                         fmaxf(fmaxf(s1[0], s1[1]), fmaxf(s1[2], s1[3])));
        tm = fmaxf(tm, __shfl_xor(tm, 16, 64));
        tm = fmaxf(tm, __shfl_xor(tm, 32, 64));
        float al = 1.0f;
        if (__ballot(tm > m_r + 12.0f)) {
          float mn = fmaxf(m_r, tm);
          al = exp2f(m_r - mn);
          l_r *= al;
          m_r = mn;
        }
        float p0[4], p1[4], rs = 0.f;
#pragma unroll
        for (int r = 0; r < 4; ++r) {
          p0[r] = exp2f(s0[r] - m_r);
          p1[r] = exp2f(s1[r] - m_r);
          rs += p0[r] + p1[r];
        }
        rs += __shfl_xor(rs, 16, 64);
        rs += __shfl_xor(rs, 32, 64);
        l_r += rs;

        // ---- P^T -> pair LDS [q32 = ph*16+lp][key]; alpha -> Axf ----
        *(uint2*)&Pp[p][ph*16 + lp][quad * 4] =
            make_uint2(f2bf2(p0[0], p0[1]), f2bf2(p0[2], p0[3]));
        *(uint2*)&Pp[p][ph*16 + lp][16 + quad * 4] =
            make_uint2(f2bf2(p1[0], p1[1]), f2bf2(p1[2], p1[3]));
        if (lane < 16) Axf[p][ph*16 + lane] = al;
      }

      // ---- barrier A: P/alpha pair-visible; KsT(t) landed (4 oldest); the
      //      8 newest DMAs (Ks/KsT t+1) stay in flight across the barrier ----
      if (pre) asm volatile("s_waitcnt vmcnt(8) lgkmcnt(0)" ::: "memory");
      else     asm volatile("s_waitcnt vmcnt(0) lgkmcnt(0)" ::: "memory");
      __builtin_amdgcn_s_barrier();
      __builtin_amdgcn_sched_barrier(0);

      if (t <= tmax) {
        // ---- pair-wide rescale: alpha for q32 = la (may be other wave's) --
        float alx = Axf[p][la];
        if (__ballot(alx < 1.0f)) {
#pragma unroll
          for (int ct = 0; ct < 8; ++ct)
#pragma unroll
            for (int j = 0; j < 16; ++j) O32[ct][j] *= alx;
        }

        // ---- PV 32x32x16: O^T[lat half][q32] += V^T * P ----
        short8 pb0 = frag_ld(&Pp[p][la][hi * 8]);
        short8 pb1 = frag_ld(&Pp[p][la][16 + hi * 8]);
        const bf16* KtB = KsT[bf] + pvBase;
#pragma unroll
        for (int lb = 0; lb < 8; ++lb) {
          short8 a0 = frag_ld(KtB + lb * 1024 + offk0);
          O32[lb] = __builtin_amdgcn_mfma_f32_32x32x16_bf16(a0, pb0, O32[lb], 0, 0, 0);
          short8 a1 = frag_ld(KtB + lb * 1024 + offk1);
          O32[lb] = __builtin_amdgcn_mfma_f32_32x32x16_bf16(a1, pb1, O32[lb], 0, 0, 0);
        }
      }

      // ---- barrier B: round close. Ks(t+1) landed (next 4 oldest); KsT(t+1)
      //      keeps flying into next round's barrier A ----
      if (pre) asm volatile("s_waitcnt vmcnt(4) lgkmcnt(0)" ::: "memory");
      else     asm volatile("s_waitcnt vmcnt(0) lgkmcnt(0)" ::: "memory");
      __builtin_amdgcn_s_barrier();
      __builtin_amdgcn_sched_barrier(0);
    }

    // ---- epilogue: exchange l across pair; transpose O via Ks[1] slice ----
    if (lane < 16) Axf[p][ph*16 + lane] = l_r;
    __syncthreads();                         // l visible; Ks[1]/KsT[1] dead
    {
      float linv = 1.0f / Axf[p][la];
      u32* Ex = (u32*)&Ks[1][0] + w * 640;   // per-wave [32 q][20 u32] slice
      const int qrow = lane >> 1, seg = lane & 1;
#pragma unroll
      for (int lb = 0; lb < 8; ++lb) {
        // write: lane holds 16 values for q = la; rows (reg&3)+8*(reg>>2)+4hi
#pragma unroll
        for (int rq = 0; rq < 4; ++rq) {
          float o0 = O32[lb][4*rq + 0] * linv, o1 = O32[lb][4*rq + 1] * linv;
          float o2 = O32[lb][4*rq + 2] * linv, o3 = O32[lb][4*rq + 3] * linv;
          *(uint2*)&Ex[la * 20 + rq * 4 + hi * 2] =
              make_uint2(f2bf2(o0, o1), f2bf2(o2, o3));
        }
        asm volatile("s_waitcnt lgkmcnt(0)" ::: "memory");
        uint4 v0 = *(const uint4*)&Ex[qrow * 20 + seg * 8];
        uint4 v1 = *(const uint4*)&Ex[qrow * 20 + seg * 8 + 4];
        bf16* dst = qbaseP + (long)qrow * kL + L0 + lb * 32 + seg * 16;
        *(uint4*)dst = v0;
        *(uint4*)(dst + 8) = v1;
        asm volatile("s_waitcnt lgkmcnt(0)" ::: "memory");
      }
    }
    __syncthreads();     // half boundary: epilogue done before next prologue
  }
}

// ---------------------------------------------------------------------------
extern "C" void kernel_launch(void* const* d_in, const int* in_sizes, int n_in,
                              void* d_out, int out_size, void* d_ws, size_t ws_size,
                              hipStream_t stream)
{
  const float* x     = (const float*)d_in[0];
  const float* W_dq  = (const float*)d_in[1];
  const float* W_uq  = (const float*)d_in[2];
  const float* W_dkv = (const float*)d_in[3];
  const float* W_uk  = (const float*)d_in[4];
  const float* W_uv  = (const float*)d_in[5];
  const float* W_o   = (const float*)d_in[6];

  float* y_out   = (float*)d_out;
  float* ckv_out = y_out + (long)kB * kT * kC;

  // workspace layout (max 101,711,872 B, proven bound)
  char* ws = (char*)d_ws;
  bf16* q_lat  = (bf16*)(ws + 0);            // 64 MB  (y_lat in place)
  bf16* ckv_b  = (bf16*)(ws + 67108864);     //  4 MB
  bf16* ckvT   = (bf16*)(ws + 71303168);     //  4 MB
  bf16* xb     = (bf16*)(ws + 75497472);     //  8 MB
  bf16* q_lowb = (bf16*)(ws + 83886080);     //  4 MB
  bf16* qfullb = (bf16*)(ws + 88080384);     //  8 MB (scratch overlap below)
  bf16* W_uqTb = (bf16*)(ws + 88080384);     //  1 MB  [dead before qfullb write]
  bf16* W_ukTb = (bf16*)(ws + 89128960);     //  1 MB
  bf16* W_uvTb = (bf16*)(ws + 90177536);     //  1 MB
  bf16* W_dqTb = (bf16*)(ws + 91226112);     //  1 MB
  bf16* W_ob   = (bf16*)(ws + 92274688);     //  2 MB
  bf16* tmpT   = (bf16*)(ws + 94371840);     // 0.5 MB
  bf16* k_effT = (bf16*)(ws + 96468992);     //  1 MB  [512 l][1024 c]
  bf16* v_effT = (bf16*)(ws + 97517568);     //  1 MB  [1024 j][512 l]
  bf16* W_dqb  = (bf16*)(ws + 98566144);     //  1 MB
  bf16* W_uqb  = (bf16*)(ws + 99614720);     //  1 MB
  bf16* W_dkvb = (bf16*)(ws + 100663296);    //  1 MB

  const dim3 blk(256);
  const long TC = (long)kT * kC, TL = (long)kT * kL;
  const float kScale = 0.125f * 1.44269504088896f;   // 1/sqrt(hs) * log2(e)

  casts_all<<<dim3(6656), blk, 0, stream>>>(
      x, W_dq, W_uq, W_dkv, W_o, xb, W_dqb, W_uqb, W_dkvb, W_ob);
  tcasts_all<<<dim3(32, 32, 4), blk, 0, stream>>>(
      W_uq, W_uk, W_uv, W_dq, W_uqTb, W_ukTb, W_uvTb, W_dqTb);

  mm_nt<bf16><<<dim3(8, 8, 1), blk, 0, stream>>>(
      W_ukTb, 1024, 0, 0, W_uqTb, 1024, 0, 0, tmpT, 512, 0, 0, 1024, 1.0f);
  mm_nt<bf16><<<dim3(8, 16, 1), blk, 0, stream>>>(
      tmpT, 512, 0, 0, W_dqTb, 512, 0, 0, k_effT, 1024, 0, 0, 512, kScale);
  mm_nt<bf16><<<dim3(16, 8, 1), blk, 0, stream>>>(
      W_ob, 1024, 0, 0, W_uvTb, 1024, 0, 0, v_effT, 512, 0, 0, 1024, 1.0f);
  mm_nt<bf16><<<dim3(64, 8, 1), blk, 0, stream>>>(
      xb, 1024, 0, 0, W_dqb, 1024, 0, 0, q_lowb, 512, 0, 0, 1024, 1.0f);
  mm_nt<bf16><<<dim3(64, 16, 1), blk, 0, stream>>>(
      q_lowb, 512, 0, 0, W_uqb, 512, 0, 0, qfullb, 1024, 0, 0, 512, 1.0f);
  // c_kv -> bf16 ckv_b directly (no early d_out write)
  mm_nt<bf16><<<dim3(64, 8, 1), blk, 0, stream>>>(
      xb, 1024, 0, 0, W_dkvb, 1024, 0, 0, ckv_b, 512, 0, 0, 1024, 1.0f);
  transpose_ckv<<<dim3(64, 16, 2), blk, 0, stream>>>(ckv_b, ckvT);
  mm_nt<bf16><<<dim3(32, 8, 32), blk, 0, stream>>>(
      qfullb, 1024, TC, 64,
      k_effT, 1024, 0, 64,
      q_lat, 512, (long)kNH * TL, TL,
      64, 1.0f);
  flash_mfma<<<dim3(8, 16, 2), dim3(512), 0, stream>>>(q_lat, ckv_b, ckvT);
  mm_nt<float><<<dim3(32, 1, 32), blk, 0, stream>>>(
      q_lat, 512, (long)kNH * TL, TL,
      v_effT, 512, 0, (long)64 * 512,
      y_out, 1024, TC, 64,
      512, 1.0f);
  // FINAL kernel: write the fp32 c_kv output tail last.
  upcast_kernel<<<dim3(2048), blk, 0, stream>>>(ckv_b, ckv_out, 2097152);

  (void)in_sizes; (void)n_in; (void)out_size; (void)ws_size;
}

// Round 7
// 263.530 us; speedup vs baseline: 1.6440x; 1.6440x over previous
//
#include <hip/hip_runtime.h>
#include <hip/hip_bf16.h>

// MLA absorbed causal attention, MI355X round 12:
//  v10: DE-ABSORBED attention. The absorbed path (S over 512-dim latent) is
//  4x the FLOPs of standard MHA for prefill. Precompute per-(b,h):
//    K_head[t][d] = kScale * sum_l ckv[t][l] k_eff[h][d][l]   (T x 64)
//    V_headT[d][t] =         sum_l v_eff^T[h][d][l] ckv[t][l] (64 x T)
//  then flash64 = standard hs=64 causal flash (17.2 GFLOP vs 110), writing
//  y fp32 directly. Deletes q_lat (64MB), y GEMM, transpose_ckv.
// fp32 I/O. d_out = [ y (2*2048*1024) | c_kv (2*2048*512) ] fp32.

using bf16 = __hip_bfloat16;
using u32  = unsigned int;
using short8 = __attribute__((ext_vector_type(8))) short;   // 8 bf16 (4 VGPRs)
using f4     = __attribute__((ext_vector_type(4))) float;   // 16x16 accumulator

static constexpr int kB  = 2;
static constexpr int kT  = 2048;
static constexpr int kC  = 1024;
static constexpr int kNH = 16;
static constexpr int kL  = 512;

__device__ inline u32 f2bf2(float a, float b) {
  bf16 ha = __float2bfloat16(a), hb = __float2bfloat16(b);
  unsigned short ua, ub;
  __builtin_memcpy(&ua, &ha, 2);
  __builtin_memcpy(&ub, &hb, 2);
  return (u32)ua | ((u32)ub << 16);
}
__device__ inline unsigned short f2bf(float x) {
  bf16 h = __float2bfloat16(x);
  unsigned short u; __builtin_memcpy(&u, &h, 2);
  return u;
}
__device__ inline short8 frag_ld(const void* p) {   // 16B aligned -> ds/global b128
  short8 r; __builtin_memcpy(&r, p, 16); return r;
}
// async global->LDS DMA, 16 B/lane. dest = wave-uniform base + lane*16.
__device__ inline void g2lds16(const bf16* g, bf16* l) {
  __builtin_amdgcn_global_load_lds(
      (const __attribute__((address_space(1))) u32*)g,
      (__attribute__((address_space(3))) u32*)l, 16, 0, 0);
}

// ---- fused flat casts: x, W_dq, W_uq, W_dkv, W_o -> bf16 ----
__global__ __launch_bounds__(256)
void casts_all(const float* __restrict__ x,   const float* __restrict__ wdq,
               const float* __restrict__ wuq, const float* __restrict__ wdkv,
               const float* __restrict__ wo,
               bf16* __restrict__ xb,   bf16* __restrict__ wdqb,
               bf16* __restrict__ wuqb, bf16* __restrict__ wdkvb,
               bf16* __restrict__ wob)
{
  long i = (long)(blockIdx.x * 256 + threadIdx.x) * 4;
  const float* s; bf16* d; long off;
  if      (i < 4194304) { s = x;    d = xb;    off = i; }
  else if (i < 4718592) { s = wdq;  d = wdqb;  off = i - 4194304; }
  else if (i < 5242880) { s = wuq;  d = wuqb;  off = i - 4718592; }
  else if (i < 5767168) { s = wdkv; d = wdkvb; off = i - 5242880; }
  else                  { s = wo;   d = wob;   off = i - 5767168; }
  float4 v = *(const float4*)(s + off);
  *(uint2*)((u32*)d + off / 2) = make_uint2(f2bf2(v.x, v.y), f2bf2(v.z, v.w));
}

// bf16 -> fp32 upcast (final c_kv output write). n multiple of 1024.
__global__ __launch_bounds__(256)
void upcast_kernel(const bf16* __restrict__ src, float* __restrict__ dst, int n)
{
  int i = (blockIdx.x * 256 + threadIdx.x) * 4;
  if (i < n) {
    uint2 v = *(const uint2*)((const u32*)src + i / 2);
    float4 o;
    o.x = __uint_as_float(v.x << 16);
    o.y = __uint_as_float(v.x & 0xffff0000u);
    o.z = __uint_as_float(v.y << 16);
    o.w = __uint_as_float(v.y & 0xffff0000u);
    *(float4*)(dst + i) = o;
  }
}

// ---- fused transpose-casts: z selects (src,dst,R,C); guards for shape ----
__global__ __launch_bounds__(256)
void tcasts_all(const float* __restrict__ wuq, const float* __restrict__ wuk,
                const float* __restrict__ wuv, const float* __restrict__ wdq,
                bf16* __restrict__ uqT, bf16* __restrict__ ukT,
                bf16* __restrict__ uvT, bf16* __restrict__ dqT)
{
  const int z = blockIdx.z;
  const float* src = z == 0 ? wuq : z == 1 ? wuk : z == 2 ? wuv : wdq;
  bf16* dst        = z == 0 ? uqT : z == 1 ? ukT : z == 2 ? uvT : dqT;
  const int R = (z == 3) ? 512 : 1024, C = (z == 3) ? 1024 : 512;
  const int r0 = blockIdx.x * 32, c0 = blockIdx.y * 32;
  if (r0 >= R || c0 >= C) return;
  __shared__ float s[32][33];
  const int x = threadIdx.x & 31, y = threadIdx.x >> 5;   // y: 0..7
#pragma unroll
  for (int i = 0; i < 4; ++i)
    s[y*4 + i][x] = src[(long)(r0 + y*4 + i) * C + c0 + x];
  __syncthreads();
  unsigned short* dp = (unsigned short*)dst;
#pragma unroll
  for (int i = 0; i < 4; ++i)
    dp[(long)(c0 + y*4 + i) * R + r0 + x] = f2bf(s[x][y*4 + i]);
}

// ---------------------------------------------------------------------------
// NT MFMA GEMM (round-3 proven): C[m][n] = alpha * sum_k A[m][k] * B[n][k].
// ---------------------------------------------------------------------------
template<typename TCe>
__global__ __launch_bounds__(256)
void mm_nt(const bf16* __restrict__ A, int lda, long aHi, long aLo,
           const bf16* __restrict__ Bm, int ldb, long bHi, long bLo,
           TCe* __restrict__ Cm, int ldc, long cHi, long cLo,
           int K, float alpha)
{
  const int z = blockIdx.z;
  A  += (long)(z >> 4) * aHi + (long)(z & 15) * aLo;
  Bm += (long)(z >> 4) * bHi + (long)(z & 15) * bLo;
  Cm += (long)(z >> 4) * cHi + (long)(z & 15) * cLo;

  __shared__ __align__(16) bf16 As[64][72];
  __shared__ __align__(16) bf16 Bs[64][72];

  const int tid = threadIdx.x;
  const int w = tid >> 6, lane = tid & 63;
  const int quad = lane >> 4, lp = lane & 15;
  const int m0 = blockIdx.x * 64, n0 = blockIdx.y * 64;
  const int row = tid >> 2, cseg = (tid & 3) * 16;

  f4 acc[4];
#pragma unroll
  for (int i = 0; i < 4; ++i) acc[i] = f4{0.f, 0.f, 0.f, 0.f};

  for (int k0 = 0; k0 < K; k0 += 64) {
    const bf16* ag = A  + (long)(m0 + row) * lda + k0 + cseg;
    const bf16* bg = Bm + (long)(n0 + row) * ldb + k0 + cseg;
    uint4 a0 = *(const uint4*)ag, a1 = *(const uint4*)(ag + 8);
    uint4 b0 = *(const uint4*)bg, b1 = *(const uint4*)(bg + 8);
    __syncthreads();
    *(uint4*)&As[row][cseg] = a0; *(uint4*)&As[row][cseg + 8] = a1;
    *(uint4*)&Bs[row][cseg] = b0; *(uint4*)&Bs[row][cseg + 8] = b1;
    __syncthreads();

    short8 af0 = frag_ld(&As[w*16 + lp][quad * 8]);
    short8 af1 = frag_ld(&As[w*16 + lp][32 + quad * 8]);
#pragma unroll
    for (int nb = 0; nb < 4; ++nb) {
      short8 bf0 = frag_ld(&Bs[nb*16 + lp][quad * 8]);
      short8 bf1 = frag_ld(&Bs[nb*16 + lp][32 + quad * 8]);
      acc[nb] = __builtin_amdgcn_mfma_f32_16x16x32_bf16(af0, bf0, acc[nb], 0, 0, 0);
      acc[nb] = __builtin_amdgcn_mfma_f32_16x16x32_bf16(af1, bf1, acc[nb], 0, 0, 0);
    }
  }
#pragma unroll
  for (int nb = 0; nb < 4; ++nb)
#pragma unroll
    for (int r = 0; r < 4; ++r) {
      float v = alpha * acc[nb][r];
      long off = (long)(m0 + w*16 + quad*4 + r) * ldc + n0 + nb*16 + lp;
      if constexpr (__is_same(TCe, float)) Cm[off] = v;
      else ((unsigned short*)Cm)[off] = f2bf(v);
    }
}

// ---------------------------------------------------------------------------
// flash64: standard hs=64 causal flash attention over de-absorbed K/V.
// Grid (16,16,2): s = 15-bx (big stripes first), h = by, b = bz. 512 WGs.
// Block 512 = 8 waves; wave w owns queries q0 = s*128 + w*16 .. +15.
// Round t: keys [64t, 64t+63]; nt = 2s+2; wave active while t <= tmaxw,
// tmaxw = 2s + (w>=4). Diagonal mask at t == tmaxw.
// LDS: Kt[2][64][64] (key,d), Vt[2][64][64] (d,trel) — both 16B-block-XOR
// swizzled (phys = logical ^ (row&7)) via pre-swizzled DMA source; Pb per
// wave [16 q][72 key-pad]. 50 KB total; __launch_bounds__(512,4) -> 2 WG/CU.
// MFMA 16x16x32: QK A=Kt rows (m=key), B=Q (n=q, lane-local lp);
// PV A=Vt rows (m=d), B=P (n=q). C layout: col=lp, row=quad*4+r.
// Epilogue: y[q][h*64+d] fp32 direct (lane holds q=lp, d=db*16+quad*4+r).
// ---------------------------------------------------------------------------
__global__ __launch_bounds__(512, 4)
void flash64(const bf16* __restrict__ qfull, const bf16* __restrict__ Kh,
             const bf16* __restrict__ VhT, float* __restrict__ y)
{
  const int s = 15 - (int)blockIdx.x;
  const int h = blockIdx.y, b = blockIdx.z;
  const int tid = threadIdx.x;
  const int w = tid >> 6, lane = tid & 63;
  const int quad = lane >> 4, lp = lane & 15;

  __shared__ __align__(16) bf16 Kt[2][64 * 64];        // 16 KB
  __shared__ __align__(16) bf16 Vt[2][64 * 64];        // 16 KB
  __shared__ __align__(16) bf16 Pb[8][16 * 72];        // 18 KB

  bf16* Pw = &Pb[w][0];

  const long bh = (long)b * kNH + h;
  const int q0 = s * 128 + w * 16;

  // Q fragments (B-operand): [q=lp][d-seg]; d 0..31 -> qf0, 32..63 -> qf1
  const bf16* qp = qfull + ((long)b * kT + q0 + lp) * kC + h * 64 + quad * 8;
  const short8 qf0 = frag_ld(qp);
  const short8 qf1 = frag_ld(qp + 32);

  // staging: lane stages tile row rk = w*8 + lane/8, phys block = lane&7;
  // source pre-swizzled so LDS phys block pb holds logical pb ^ (rk&7).
  const int rk = w * 8 + (lane >> 3), blk = lane & 7;
  const int soff = ((blk ^ (rk & 7)) * 8);
  const bf16* kSrc = Kh  + (bh * kT + rk) * 64 + soff;
  const bf16* vSrc = VhT + (bh * 64 + rk) * (long)kT + soff;

  // A-frag lane constants: addr = row*64 + ((blkL)^(lp&7))*8, blkL = ds*4+quad
  const int swz = lp & 7;
  const int lp64 = lp * 64;
  const int B0 = ((0 + quad) ^ swz) * 8;               // d/k seg 0..31
  const int B1 = ((4 + quad) ^ swz) * 8;               // d/k seg 32..63

  const int tmaxw = 2 * s + ((w >> 2) ? 1 : 0);
  const int nt = 2 * s + 2;

  f4 O0 = f4{0,0,0,0}, O1 = f4{0,0,0,0}, O2 = f4{0,0,0,0}, O3 = f4{0,0,0,0};
  float m_r = -3e38f, l_r = 0.f;

  // prologue: stage tile 0 into buffer 0 (also drains qf loads)
  g2lds16(kSrc, &Kt[0][w * 512]);
  g2lds16(vSrc, &Vt[0][w * 512]);
  asm volatile("s_waitcnt vmcnt(0)" ::: "memory");
  __builtin_amdgcn_s_barrier();

  for (int t = 0; t < nt; ++t) {
    const int bf = t & 1;
    if (t + 1 < nt) {                      // stage t+1 (in flight during compute)
      g2lds16(kSrc + (long)(t + 1) * 4096, &Kt[bf ^ 1][w * 512]);
      g2lds16(vSrc + (t + 1) * 64,         &Vt[bf ^ 1][w * 512]);
    }

    if (t <= tmaxw) {
      // ---- QK: S^T[key][q], 4 key-tiles x 2 d-steps ----
      const bf16* KB = &Kt[bf][0];
      f4 s0 = f4{0,0,0,0}, s1 = f4{0,0,0,0}, s2 = f4{0,0,0,0}, s3 = f4{0,0,0,0};
      {
        short8 a;
        a = frag_ld(KB +    0 + lp64 + B0); s0 = __builtin_amdgcn_mfma_f32_16x16x32_bf16(a, qf0, s0, 0, 0, 0);
        a = frag_ld(KB +    0 + lp64 + B1); s0 = __builtin_amdgcn_mfma_f32_16x16x32_bf16(a, qf1, s0, 0, 0, 0);
        a = frag_ld(KB + 1024 + lp64 + B0); s1 = __builtin_amdgcn_mfma_f32_16x16x32_bf16(a, qf0, s1, 0, 0, 0);
        a = frag_ld(KB + 1024 + lp64 + B1); s1 = __builtin_amdgcn_mfma_f32_16x16x32_bf16(a, qf1, s1, 0, 0, 0);
        a = frag_ld(KB + 2048 + lp64 + B0); s2 = __builtin_amdgcn_mfma_f32_16x16x32_bf16(a, qf0, s2, 0, 0, 0);
        a = frag_ld(KB + 2048 + lp64 + B1); s2 = __builtin_amdgcn_mfma_f32_16x16x32_bf16(a, qf1, s2, 0, 0, 0);
        a = frag_ld(KB + 3072 + lp64 + B0); s3 = __builtin_amdgcn_mfma_f32_16x16x32_bf16(a, qf0, s3, 0, 0, 0);
        a = frag_ld(KB + 3072 + lp64 + B1); s3 = __builtin_amdgcn_mfma_f32_16x16x32_bf16(a, qf1, s3, 0, 0, 0);
      }

      // ---- causal mask (diagonal round): key = 64t + kt*16 + quad*4 + r ----
      if (t == tmaxw) {
        const int kb = t * 64, q = q0 + lp;
#pragma unroll
        for (int r = 0; r < 4; ++r) {
          if (kb +      quad * 4 + r > q) s0[r] = -3e38f;
          if (kb + 16 + quad * 4 + r > q) s1[r] = -3e38f;
          if (kb + 32 + quad * 4 + r > q) s2[r] = -3e38f;
          if (kb + 48 + quad * 4 + r > q) s3[r] = -3e38f;
        }
      }

      // ---- online softmax (q = lp lane-local; cross-quad shfl), defer-max --
      float tm = fmaxf(fmaxf(fmaxf(s0[0], s0[1]), fmaxf(s0[2], s0[3])),
                       fmaxf(fmaxf(s1[0], s1[1]), fmaxf(s1[2], s1[3])));
      tm = fmaxf(tm, fmaxf(fmaxf(fmaxf(s2[0], s2[1]), fmaxf(s2[2], s2[3])),
                           fmaxf(fmaxf(s3[0], s3[1]), fmaxf(s3[2], s3[3]))));
      tm = fmaxf(tm, __shfl_xor(tm, 16, 64));
      tm = fmaxf(tm, __shfl_xor(tm, 32, 64));
      if (__ballot(tm > m_r + 12.0f)) {
        float mn = fmaxf(m_r, tm);
        float al = exp2f(m_r - mn);
        l_r *= al; m_r = mn;
#pragma unroll
        for (int j = 0; j < 4; ++j) {
          O0[j] *= al; O1[j] *= al; O2[j] *= al; O3[j] *= al;
        }
      }
      float p0[4], p1[4], p2[4], p3[4], rs = 0.f;
#pragma unroll
      for (int r = 0; r < 4; ++r) {
        p0[r] = exp2f(s0[r] - m_r); p1[r] = exp2f(s1[r] - m_r);
        p2[r] = exp2f(s2[r] - m_r); p3[r] = exp2f(s3[r] - m_r);
        rs += p0[r] + p1[r] + p2[r] + p3[r];
      }
      rs += __shfl_xor(rs, 16, 64);
      rs += __shfl_xor(rs, 32, 64);
      l_r += rs;

      // ---- P -> per-wave LDS [q=lp][key], unswizzled, row pad 72 ----
      {
        bf16* pr = Pw + lp * 72 + quad * 4;
        *(uint2*)(pr)      = make_uint2(f2bf2(p0[0], p0[1]), f2bf2(p0[2], p0[3]));
        *(uint2*)(pr + 16) = make_uint2(f2bf2(p1[0], p1[1]), f2bf2(p1[2], p1[3]));
        *(uint2*)(pr + 32) = make_uint2(f2bf2(p2[0], p2[1]), f2bf2(p2[2], p2[3]));
        *(uint2*)(pr + 48) = make_uint2(f2bf2(p3[0], p3[1]), f2bf2(p3[2], p3[3]));
      }
      asm volatile("s_waitcnt lgkmcnt(0)" ::: "memory");
      short8 pb0 = frag_ld(Pw + lp * 72 + quad * 8);        // keys 0..31 seg
      short8 pb1 = frag_ld(Pw + lp * 72 + 32 + quad * 8);   // keys 32..63 seg

      // ---- PV: O^T[d][q] += V^T * P, 4 d-tiles x 2 k-steps ----
      const bf16* VB = &Vt[bf][0];
      {
        short8 a;
        a = frag_ld(VB +    0 + lp64 + B0); O0 = __builtin_amdgcn_mfma_f32_16x16x32_bf16(a, pb0, O0, 0, 0, 0);
        a = frag_ld(VB +    0 + lp64 + B1); O0 = __builtin_amdgcn_mfma_f32_16x16x32_bf16(a, pb1, O0, 0, 0, 0);
        a = frag_ld(VB + 1024 + lp64 + B0); O1 = __builtin_amdgcn_mfma_f32_16x16x32_bf16(a, pb0, O1, 0, 0, 0);
        a = frag_ld(VB + 1024 + lp64 + B1); O1 = __builtin_amdgcn_mfma_f32_16x16x32_bf16(a, pb1, O1, 0, 0, 0);
        a = frag_ld(VB + 2048 + lp64 + B0); O2 = __builtin_amdgcn_mfma_f32_16x16x32_bf16(a, pb0, O2, 0, 0, 0);
        a = frag_ld(VB + 2048 + lp64 + B1); O2 = __builtin_amdgcn_mfma_f32_16x16x32_bf16(a, pb1, O2, 0, 0, 0);
        a = frag_ld(VB + 3072 + lp64 + B0); O3 = __builtin_amdgcn_mfma_f32_16x16x32_bf16(a, pb0, O3, 0, 0, 0);
        a = frag_ld(VB + 3072 + lp64 + B1); O3 = __builtin_amdgcn_mfma_f32_16x16x32_bf16(a, pb1, O3, 0, 0, 0);
      }
    }

    // round close: tile t reads done everywhere; t+1 DMAs (in flight since
    // round start) drain here — latency covered by the compute above.
    asm volatile("s_waitcnt vmcnt(0)" ::: "memory");
    __builtin_amdgcn_s_barrier();
    __builtin_amdgcn_sched_barrier(0);
  }

  // ---- epilogue: y[q][h*64+d] = O^T * (1/l) — lane-local, direct fp32 ----
  {
    const float inv = 1.0f / l_r;
    float* yp = y + ((long)b * kT + q0 + lp) * kC + h * 64 + quad * 4;
    *(float4*)(yp +  0) = float4{O0[0]*inv, O0[1]*inv, O0[2]*inv, O0[3]*inv};
    *(float4*)(yp + 16) = float4{O1[0]*inv, O1[1]*inv, O1[2]*inv, O1[3]*inv};
    *(float4*)(yp + 32) = float4{O2[0]*inv, O2[1]*inv, O2[2]*inv, O2[3]*inv};
    *(float4*)(yp + 48) = float4{O3[0]*inv, O3[1]*inv, O3[2]*inv, O3[3]*inv};
  }
}

// ---------------------------------------------------------------------------
extern "C" void kernel_launch(void* const* d_in, const int* in_sizes, int n_in,
                              void* d_out, int out_size, void* d_ws, size_t ws_size,
                              hipStream_t stream)
{
  const float* x     = (const float*)d_in[0];
  const float* W_dq  = (const float*)d_in[1];
  const float* W_uq  = (const float*)d_in[2];
  const float* W_dkv = (const float*)d_in[3];
  const float* W_uk  = (const float*)d_in[4];
  const float* W_uv  = (const float*)d_in[5];
  const float* W_o   = (const float*)d_in[6];

  float* y_out   = (float*)d_out;
  float* ckv_out = y_out + (long)kB * kT * kC;

  // workspace layout (~52 MB)
  char* ws = (char*)d_ws;
  bf16* xb      = (bf16*)(ws + 0);           //  8 MB
  bf16* qfullb  = (bf16*)(ws + 8388608);     //  8 MB
  bf16* q_lowb  = (bf16*)(ws + 16777216);    //  4 MB
  bf16* ckv_b   = (bf16*)(ws + 20971520);    //  4 MB
  bf16* K_head  = (bf16*)(ws + 25165824);    //  8 MB (B,NH,T,64)
  bf16* V_headT = (bf16*)(ws + 33554432);    //  8 MB (B,NH,64,T)
  bf16* W_dqb   = (bf16*)(ws + 41943040);    //  1 MB
  bf16* W_uqb   = (bf16*)(ws + 42991616);    //  1 MB
  bf16* W_dkvb  = (bf16*)(ws + 44040192);    //  1 MB
  bf16* W_ob    = (bf16*)(ws + 45088768);    //  2 MB
  bf16* W_uqTb  = (bf16*)(ws + 47185920);    //  1 MB
  bf16* W_ukTb  = (bf16*)(ws + 48234496);    //  1 MB
  bf16* W_uvTb  = (bf16*)(ws + 49283072);    //  1 MB
  bf16* W_dqTb  = (bf16*)(ws + 50331648);    //  1 MB
  bf16* tmpT    = (bf16*)(ws + 51380224);    // 0.5 MB
  bf16* k_effF  = (bf16*)(ws + 51904512);    //  1 MB (1024 c x 512 l)
  bf16* v_effT  = (bf16*)(ws + 52953088);    //  1 MB (1024 j x 512 l)

  const dim3 blk(256);
  const long TL = (long)kT * kL;
  const float kScale = 0.125f * 1.44269504088896f;   // 1/sqrt(64) * log2(e)

  casts_all<<<dim3(6656), blk, 0, stream>>>(
      x, W_dq, W_uq, W_dkv, W_o, xb, W_dqb, W_uqb, W_dkvb, W_ob);
  tcasts_all<<<dim3(32, 32, 4), blk, 0, stream>>>(
      W_uq, W_uk, W_uv, W_dq, W_uqTb, W_ukTb, W_uvTb, W_dqTb);

  // tmpT[l][q] = (W_uk^T W_uq)[l][q]
  mm_nt<bf16><<<dim3(8, 8, 1), blk, 0, stream>>>(
      W_ukTb, 1024, 0, 0, W_uqTb, 1024, 0, 0, tmpT, 512, 0, 0, 1024, 1.0f);
  // k_effF[c][l] = (W_dq^T W_uq^T W_uk)[c][l]
  mm_nt<bf16><<<dim3(16, 8, 1), blk, 0, stream>>>(
      W_dqTb, 512, 0, 0, tmpT, 512, 0, 0, k_effF, 512, 0, 0, 512, 1.0f);
  // v_effT[j][l] = (W_uv^T W_o^T)^T[j][l]
  mm_nt<bf16><<<dim3(16, 8, 1), blk, 0, stream>>>(
      W_ob, 1024, 0, 0, W_uvTb, 1024, 0, 0, v_effT, 512, 0, 0, 1024, 1.0f);
  // q_low = x @ W_dq^T ; qfull = q_low @ W_uq^T
  mm_nt<bf16><<<dim3(64, 8, 1), blk, 0, stream>>>(
      xb, 1024, 0, 0, W_dqb, 1024, 0, 0, q_lowb, 512, 0, 0, 1024, 1.0f);
  mm_nt<bf16><<<dim3(64, 16, 1), blk, 0, stream>>>(
      q_lowb, 512, 0, 0, W_uqb, 512, 0, 0, qfullb, 1024, 0, 0, 512, 1.0f);
  // c_kv = x @ W_dkv^T (bf16)
  mm_nt<bf16><<<dim3(64, 8, 1), blk, 0, stream>>>(
      xb, 1024, 0, 0, W_dkvb, 1024, 0, 0, ckv_b, 512, 0, 0, 1024, 1.0f);
  // K_head[b,h][t][d] = kScale * sum_l ckv[b][t][l] * k_effF[h*64+d][l]
  mm_nt<bf16><<<dim3(32, 1, 32), blk, 0, stream>>>(
      ckv_b, 512, TL, 0,
      k_effF, 512, 0, (long)64 * 512,
      K_head, 64, (long)kNH * kT * 64, (long)kT * 64,
      512, kScale);
  // V_headT[b,h][d][t] = sum_l v_effT[h*64+d][l] * ckv[b][t][l]
  mm_nt<bf16><<<dim3(1, 32, 32), blk, 0, stream>>>(
      v_effT, 512, 0, (long)64 * 512,
      ckv_b, 512, TL, 0,
      V_headT, kT, (long)kNH * 64 * kT, (long)64 * kT,
      512, 1.0f);
  // flash: y fp32 direct
  flash64<<<dim3(16, 16, 2), dim3(512), 0, stream>>>(
      qfullb, K_head, V_headT, y_out);
  // FINAL kernel: write the fp32 c_kv output tail last.
  upcast_kernel<<<dim3(2048), blk, 0, stream>>>(ckv_b, ckv_out, 2097152);

  (void)in_sizes; (void)n_in; (void)out_size; (void)ws_size;
}

// Round 8
// 239.906 us; speedup vs baseline: 1.8059x; 1.0985x over previous
//
#include <hip/hip_runtime.h>
#include <hip/hip_bf16.h>

// MLA absorbed causal attention, MI355X round 13:
//  v11: v10 + flash64 load balance + triple-buffer staging.
//  (a) BALANCE: old grid paired same-stripe WGs on one CU (id & id+256 same s)
//      -> tail CUs did 64 round-slots vs 4. New 1D grid 512: CU gets stripes
//      s and 15-s -> uniform 34 rounds/CU.
//  (b) 3-deep K/V buffers + counted vmcnt(2) at round close: tile t+1's DMAs
//      get a full extra round to land (was: force-drain same-round vmcnt(0)).
// fp32 I/O. d_out = [ y (2*2048*1024) | c_kv (2*2048*512) ] fp32.

using bf16 = __hip_bfloat16;
using u32  = unsigned int;
using short8 = __attribute__((ext_vector_type(8))) short;   // 8 bf16 (4 VGPRs)
using f4     = __attribute__((ext_vector_type(4))) float;   // 16x16 accumulator

static constexpr int kB  = 2;
static constexpr int kT  = 2048;
static constexpr int kC  = 1024;
static constexpr int kNH = 16;
static constexpr int kL  = 512;

__device__ inline u32 f2bf2(float a, float b) {
  bf16 ha = __float2bfloat16(a), hb = __float2bfloat16(b);
  unsigned short ua, ub;
  __builtin_memcpy(&ua, &ha, 2);
  __builtin_memcpy(&ub, &hb, 2);
  return (u32)ua | ((u32)ub << 16);
}
__device__ inline unsigned short f2bf(float x) {
  bf16 h = __float2bfloat16(x);
  unsigned short u; __builtin_memcpy(&u, &h, 2);
  return u;
}
__device__ inline short8 frag_ld(const void* p) {   // 16B aligned -> ds/global b128
  short8 r; __builtin_memcpy(&r, p, 16); return r;
}
// async global->LDS DMA, 16 B/lane. dest = wave-uniform base + lane*16.
__device__ inline void g2lds16(const bf16* g, bf16* l) {
  __builtin_amdgcn_global_load_lds(
      (const __attribute__((address_space(1))) u32*)g,
      (__attribute__((address_space(3))) u32*)l, 16, 0, 0);
}

// ---- fused flat casts: x, W_dq, W_uq, W_dkv, W_o -> bf16 ----
__global__ __launch_bounds__(256)
void casts_all(const float* __restrict__ x,   const float* __restrict__ wdq,
               const float* __restrict__ wuq, const float* __restrict__ wdkv,
               const float* __restrict__ wo,
               bf16* __restrict__ xb,   bf16* __restrict__ wdqb,
               bf16* __restrict__ wuqb, bf16* __restrict__ wdkvb,
               bf16* __restrict__ wob)
{
  long i = (long)(blockIdx.x * 256 + threadIdx.x) * 4;
  const float* s; bf16* d; long off;
  if      (i < 4194304) { s = x;    d = xb;    off = i; }
  else if (i < 4718592) { s = wdq;  d = wdqb;  off = i - 4194304; }
  else if (i < 5242880) { s = wuq;  d = wuqb;  off = i - 4718592; }
  else if (i < 5767168) { s = wdkv; d = wdkvb; off = i - 5242880; }
  else                  { s = wo;   d = wob;   off = i - 5767168; }
  float4 v = *(const float4*)(s + off);
  *(uint2*)((u32*)d + off / 2) = make_uint2(f2bf2(v.x, v.y), f2bf2(v.z, v.w));
}

// bf16 -> fp32 upcast (final c_kv output write). n multiple of 1024.
__global__ __launch_bounds__(256)
void upcast_kernel(const bf16* __restrict__ src, float* __restrict__ dst, int n)
{
  int i = (blockIdx.x * 256 + threadIdx.x) * 4;
  if (i < n) {
    uint2 v = *(const uint2*)((const u32*)src + i / 2);
    float4 o;
    o.x = __uint_as_float(v.x << 16);
    o.y = __uint_as_float(v.x & 0xffff0000u);
    o.z = __uint_as_float(v.y << 16);
    o.w = __uint_as_float(v.y & 0xffff0000u);
    *(float4*)(dst + i) = o;
  }
}

// ---- fused transpose-casts: z selects (src,dst,R,C); guards for shape ----
__global__ __launch_bounds__(256)
void tcasts_all(const float* __restrict__ wuq, const float* __restrict__ wuk,
                const float* __restrict__ wuv, const float* __restrict__ wdq,
                bf16* __restrict__ uqT, bf16* __restrict__ ukT,
                bf16* __restrict__ uvT, bf16* __restrict__ dqT)
{
  const int z = blockIdx.z;
  const float* src = z == 0 ? wuq : z == 1 ? wuk : z == 2 ? wuv : wdq;
  bf16* dst        = z == 0 ? uqT : z == 1 ? ukT : z == 2 ? uvT : dqT;
  const int R = (z == 3) ? 512 : 1024, C = (z == 3) ? 1024 : 512;
  const int r0 = blockIdx.x * 32, c0 = blockIdx.y * 32;
  if (r0 >= R || c0 >= C) return;
  __shared__ float s[32][33];
  const int x = threadIdx.x & 31, y = threadIdx.x >> 5;   // y: 0..7
#pragma unroll
  for (int i = 0; i < 4; ++i)
    s[y*4 + i][x] = src[(long)(r0 + y*4 + i) * C + c0 + x];
  __syncthreads();
  unsigned short* dp = (unsigned short*)dst;
#pragma unroll
  for (int i = 0; i < 4; ++i)
    dp[(long)(c0 + y*4 + i) * R + r0 + x] = f2bf(s[x][y*4 + i]);
}

// ---------------------------------------------------------------------------
// NT MFMA GEMM (round-3 proven): C[m][n] = alpha * sum_k A[m][k] * B[n][k].
// ---------------------------------------------------------------------------
template<typename TCe>
__global__ __launch_bounds__(256)
void mm_nt(const bf16* __restrict__ A, int lda, long aHi, long aLo,
           const bf16* __restrict__ Bm, int ldb, long bHi, long bLo,
           TCe* __restrict__ Cm, int ldc, long cHi, long cLo,
           int K, float alpha)
{
  const int z = blockIdx.z;
  A  += (long)(z >> 4) * aHi + (long)(z & 15) * aLo;
  Bm += (long)(z >> 4) * bHi + (long)(z & 15) * bLo;
  Cm += (long)(z >> 4) * cHi + (long)(z & 15) * cLo;

  __shared__ __align__(16) bf16 As[64][72];
  __shared__ __align__(16) bf16 Bs[64][72];

  const int tid = threadIdx.x;
  const int w = tid >> 6, lane = tid & 63;
  const int quad = lane >> 4, lp = lane & 15;
  const int m0 = blockIdx.x * 64, n0 = blockIdx.y * 64;
  const int row = tid >> 2, cseg = (tid & 3) * 16;

  f4 acc[4];
#pragma unroll
  for (int i = 0; i < 4; ++i) acc[i] = f4{0.f, 0.f, 0.f, 0.f};

  for (int k0 = 0; k0 < K; k0 += 64) {
    const bf16* ag = A  + (long)(m0 + row) * lda + k0 + cseg;
    const bf16* bg = Bm + (long)(n0 + row) * ldb + k0 + cseg;
    uint4 a0 = *(const uint4*)ag, a1 = *(const uint4*)(ag + 8);
    uint4 b0 = *(const uint4*)bg, b1 = *(const uint4*)(bg + 8);
    __syncthreads();
    *(uint4*)&As[row][cseg] = a0; *(uint4*)&As[row][cseg + 8] = a1;
    *(uint4*)&Bs[row][cseg] = b0; *(uint4*)&Bs[row][cseg + 8] = b1;
    __syncthreads();

    short8 af0 = frag_ld(&As[w*16 + lp][quad * 8]);
    short8 af1 = frag_ld(&As[w*16 + lp][32 + quad * 8]);
#pragma unroll
    for (int nb = 0; nb < 4; ++nb) {
      short8 bf0 = frag_ld(&Bs[nb*16 + lp][quad * 8]);
      short8 bf1 = frag_ld(&Bs[nb*16 + lp][32 + quad * 8]);
      acc[nb] = __builtin_amdgcn_mfma_f32_16x16x32_bf16(af0, bf0, acc[nb], 0, 0, 0);
      acc[nb] = __builtin_amdgcn_mfma_f32_16x16x32_bf16(af1, bf1, acc[nb], 0, 0, 0);
    }
  }
#pragma unroll
  for (int nb = 0; nb < 4; ++nb)
#pragma unroll
    for (int r = 0; r < 4; ++r) {
      float v = alpha * acc[nb][r];
      long off = (long)(m0 + w*16 + quad*4 + r) * ldc + n0 + nb*16 + lp;
      if constexpr (__is_same(TCe, float)) Cm[off] = v;
      else ((unsigned short*)Cm)[off] = f2bf(v);
    }
}

// ---------------------------------------------------------------------------
// flash64 v11: standard hs=64 causal flash, balanced grid + 3-deep staging.
// Grid 512 1D: j=id&255, hi=id>>8; h=j>>4; sl=j&15; s = hi?15-sl:sl; b=hi.
// CU pairing (id, id+256) -> stripes s and 15-s: uniform 34 rounds/CU.
// Block 512 = 8 waves; wave w owns queries q0 = s*128 + w*16 .. +15.
// Round t: keys [64t, 64t+63]; nt = 2s+2; wave active while t <= tmaxw,
// tmaxw = 2s + (w>=4). Diagonal mask at t == tmaxw.
// LDS: Kt[3][64][64], Vt[3][64][64] XOR-swizzled (phys blk = logical^ (row&7))
// via pre-swizzled DMA source; Pb per wave [16 q][72]. 67.6 KB -> 2 WG/CU.
// Staging: round t issues tile t+2 into buf (t+2)%3; round close waits
// vmcnt(2) (t+1 landed, t+2 still flying) -- vmcnt(0) only for last 2 rounds.
// MFMA 16x16x32: QK A=Kt rows (m=key), B=Q; PV A=Vt rows (m=d), B=P.
// Epilogue: y[q][h*64+d] fp32 direct.
// ---------------------------------------------------------------------------
__global__ __launch_bounds__(512, 4)
void flash64(const bf16* __restrict__ qfull, const bf16* __restrict__ Kh,
             const bf16* __restrict__ VhT, float* __restrict__ y)
{
  const int id = blockIdx.x;
  const int j = id & 255, hi2 = id >> 8;
  const int h = j >> 4, sl = j & 15;
  const int s = hi2 ? (15 - sl) : sl;
  const int b = hi2;
  const int tid = threadIdx.x;
  const int w = tid >> 6, lane = tid & 63;
  const int quad = lane >> 4, lp = lane & 15;

  __shared__ __align__(16) bf16 Kt[3][64 * 64];        // 24 KB
  __shared__ __align__(16) bf16 Vt[3][64 * 64];        // 24 KB
  __shared__ __align__(16) bf16 Pb[8][16 * 72];        // 18 KB

  bf16* Pw = &Pb[w][0];

  const long bh = (long)b * kNH + h;
  const int q0 = s * 128 + w * 16;

  // Q fragments (B-operand): [q=lp][d-seg]; d 0..31 -> qf0, 32..63 -> qf1
  const bf16* qp = qfull + ((long)b * kT + q0 + lp) * kC + h * 64 + quad * 8;
  const short8 qf0 = frag_ld(qp);
  const short8 qf1 = frag_ld(qp + 32);

  // staging: lane stages tile row rk = w*8 + lane/8, phys block = lane&7;
  // source pre-swizzled so LDS phys block pb holds logical pb ^ (rk&7).
  const int rk = w * 8 + (lane >> 3), blk = lane & 7;
  const int soff = ((blk ^ (rk & 7)) * 8);
  const bf16* kSrc = Kh  + (bh * kT + rk) * 64 + soff;
  const bf16* vSrc = VhT + (bh * 64 + rk) * (long)kT + soff;

  // A-frag lane constants: addr = row*64 + ((blkL)^(lp&7))*8, blkL = ds*4+quad
  const int swz = lp & 7;
  const int lp64 = lp * 64;
  const int B0 = ((0 + quad) ^ swz) * 8;               // d/k seg 0..31
  const int B1 = ((4 + quad) ^ swz) * 8;               // d/k seg 32..63

  const int tmaxw = 2 * s + ((w >> 2) ? 1 : 0);
  const int nt = 2 * s + 2;

  f4 O0 = f4{0,0,0,0}, O1 = f4{0,0,0,0}, O2 = f4{0,0,0,0}, O3 = f4{0,0,0,0};
  float m_r = -3e38f, l_r = 0.f;

  // prologue: stage tiles 0 and 1 (nt >= 2 always); drain through tile 0
  g2lds16(kSrc,        &Kt[0][w * 512]);
  g2lds16(vSrc,        &Vt[0][w * 512]);
  g2lds16(kSrc + 4096, &Kt[1][w * 512]);
  g2lds16(vSrc + 64,   &Vt[1][w * 512]);
  asm volatile("s_waitcnt vmcnt(2)" ::: "memory");   // qf + tile0 landed
  __builtin_amdgcn_s_barrier();
  __builtin_amdgcn_sched_barrier(0);

  for (int t = 0; t < nt; ++t) {
    const int bf = t % 3;
    const bool st2 = (t + 2 < nt);
    if (st2) {                            // stage t+2 into buf (t+2)%3
      const int b2 = (t + 2) % 3;
      g2lds16(kSrc + (long)(t + 2) * 4096, &Kt[b2][w * 512]);
      g2lds16(vSrc + (t + 2) * 64,         &Vt[b2][w * 512]);
    }

    if (t <= tmaxw) {
      // ---- QK: S^T[key][q], 4 key-tiles x 2 d-steps ----
      const bf16* KB = &Kt[bf][0];
      f4 s0 = f4{0,0,0,0}, s1 = f4{0,0,0,0}, s2 = f4{0,0,0,0}, s3 = f4{0,0,0,0};
      {
        short8 a;
        a = frag_ld(KB +    0 + lp64 + B0); s0 = __builtin_amdgcn_mfma_f32_16x16x32_bf16(a, qf0, s0, 0, 0, 0);
        a = frag_ld(KB +    0 + lp64 + B1); s0 = __builtin_amdgcn_mfma_f32_16x16x32_bf16(a, qf1, s0, 0, 0, 0);
        a = frag_ld(KB + 1024 + lp64 + B0); s1 = __builtin_amdgcn_mfma_f32_16x16x32_bf16(a, qf0, s1, 0, 0, 0);
        a = frag_ld(KB + 1024 + lp64 + B1); s1 = __builtin_amdgcn_mfma_f32_16x16x32_bf16(a, qf1, s1, 0, 0, 0);
        a = frag_ld(KB + 2048 + lp64 + B0); s2 = __builtin_amdgcn_mfma_f32_16x16x32_bf16(a, qf0, s2, 0, 0, 0);
        a = frag_ld(KB + 2048 + lp64 + B1); s2 = __builtin_amdgcn_mfma_f32_16x16x32_bf16(a, qf1, s2, 0, 0, 0);
        a = frag_ld(KB + 3072 + lp64 + B0); s3 = __builtin_amdgcn_mfma_f32_16x16x32_bf16(a, qf0, s3, 0, 0, 0);
        a = frag_ld(KB + 3072 + lp64 + B1); s3 = __builtin_amdgcn_mfma_f32_16x16x32_bf16(a, qf1, s3, 0, 0, 0);
      }

      // ---- causal mask (diagonal round): key = 64t + kt*16 + quad*4 + r ----
      if (t == tmaxw) {
        const int kb = t * 64, q = q0 + lp;
#pragma unroll
        for (int r = 0; r < 4; ++r) {
          if (kb +      quad * 4 + r > q) s0[r] = -3e38f;
          if (kb + 16 + quad * 4 + r > q) s1[r] = -3e38f;
          if (kb + 32 + quad * 4 + r > q) s2[r] = -3e38f;
          if (kb + 48 + quad * 4 + r > q) s3[r] = -3e38f;
        }
      }

      // ---- online softmax (q = lp lane-local; cross-quad shfl), defer-max --
      float tm = fmaxf(fmaxf(fmaxf(s0[0], s0[1]), fmaxf(s0[2], s0[3])),
                       fmaxf(fmaxf(s1[0], s1[1]), fmaxf(s1[2], s1[3])));
      tm = fmaxf(tm, fmaxf(fmaxf(fmaxf(s2[0], s2[1]), fmaxf(s2[2], s2[3])),
                           fmaxf(fmaxf(s3[0], s3[1]), fmaxf(s3[2], s3[3]))));
      tm = fmaxf(tm, __shfl_xor(tm, 16, 64));
      tm = fmaxf(tm, __shfl_xor(tm, 32, 64));
      if (__ballot(tm > m_r + 12.0f)) {
        float mn = fmaxf(m_r, tm);
        float al = exp2f(m_r - mn);
        l_r *= al; m_r = mn;
#pragma unroll
        for (int jj = 0; jj < 4; ++jj) {
          O0[jj] *= al; O1[jj] *= al; O2[jj] *= al; O3[jj] *= al;
        }
      }
      float p0[4], p1[4], p2[4], p3[4], rs = 0.f;
#pragma unroll
      for (int r = 0; r < 4; ++r) {
        p0[r] = exp2f(s0[r] - m_r); p1[r] = exp2f(s1[r] - m_r);
        p2[r] = exp2f(s2[r] - m_r); p3[r] = exp2f(s3[r] - m_r);
        rs += p0[r] + p1[r] + p2[r] + p3[r];
      }
      rs += __shfl_xor(rs, 16, 64);
      rs += __shfl_xor(rs, 32, 64);
      l_r += rs;

      // ---- P -> per-wave LDS [q=lp][key], unswizzled, row pad 72 ----
      {
        bf16* pr = Pw + lp * 72 + quad * 4;
        *(uint2*)(pr)      = make_uint2(f2bf2(p0[0], p0[1]), f2bf2(p0[2], p0[3]));
        *(uint2*)(pr + 16) = make_uint2(f2bf2(p1[0], p1[1]), f2bf2(p1[2], p1[3]));
        *(uint2*)(pr + 32) = make_uint2(f2bf2(p2[0], p2[1]), f2bf2(p2[2], p2[3]));
        *(uint2*)(pr + 48) = make_uint2(f2bf2(p3[0], p3[1]), f2bf2(p3[2], p3[3]));
      }
      asm volatile("s_waitcnt lgkmcnt(0)" ::: "memory");
      short8 pb0 = frag_ld(Pw + lp * 72 + quad * 8);        // keys 0..31 seg
      short8 pb1 = frag_ld(Pw + lp * 72 + 32 + quad * 8);   // keys 32..63 seg

      // ---- PV: O^T[d][q] += V^T * P, 4 d-tiles x 2 k-steps ----
      const bf16* VB = &Vt[bf][0];
      {
        short8 a;
        a = frag_ld(VB +    0 + lp64 + B0); O0 = __builtin_amdgcn_mfma_f32_16x16x32_bf16(a, pb0, O0, 0, 0, 0);
        a = frag_ld(VB +    0 + lp64 + B1); O0 = __builtin_amdgcn_mfma_f32_16x16x32_bf16(a, pb1, O0, 0, 0, 0);
        a = frag_ld(VB + 1024 + lp64 + B0); O1 = __builtin_amdgcn_mfma_f32_16x16x32_bf16(a, pb0, O1, 0, 0, 0);
        a = frag_ld(VB + 1024 + lp64 + B1); O1 = __builtin_amdgcn_mfma_f32_16x16x32_bf16(a, pb1, O1, 0, 0, 0);
        a = frag_ld(VB + 2048 + lp64 + B0); O2 = __builtin_amdgcn_mfma_f32_16x16x32_bf16(a, pb0, O2, 0, 0, 0);
        a = frag_ld(VB + 2048 + lp64 + B1); O2 = __builtin_amdgcn_mfma_f32_16x16x32_bf16(a, pb1, O2, 0, 0, 0);
        a = frag_ld(VB + 3072 + lp64 + B0); O3 = __builtin_amdgcn_mfma_f32_16x16x32_bf16(a, pb0, O3, 0, 0, 0);
        a = frag_ld(VB + 3072 + lp64 + B1); O3 = __builtin_amdgcn_mfma_f32_16x16x32_bf16(a, pb1, O3, 0, 0, 0);
      }
    }

    // round close: all waves done with tile t; tile t+1 landed (vmcnt(2):
    // only t+2's two DMAs may remain in flight). Buf t%3 is safe to rewrite
    // at t+1 (staging of t+3 issues after this barrier).
    if (st2) asm volatile("s_waitcnt vmcnt(2)" ::: "memory");
    else     asm volatile("s_waitcnt vmcnt(0)" ::: "memory");
    __builtin_amdgcn_s_barrier();
    __builtin_amdgcn_sched_barrier(0);
  }

  // ---- epilogue: y[q][h*64+d] = O^T * (1/l) — lane-local, direct fp32 ----
  {
    const float inv = 1.0f / l_r;
    float* yp = y + ((long)b * kT + q0 + lp) * kC + h * 64 + quad * 4;
    *(float4*)(yp +  0) = float4{O0[0]*inv, O0[1]*inv, O0[2]*inv, O0[3]*inv};
    *(float4*)(yp + 16) = float4{O1[0]*inv, O1[1]*inv, O1[2]*inv, O1[3]*inv};
    *(float4*)(yp + 32) = float4{O2[0]*inv, O2[1]*inv, O2[2]*inv, O2[3]*inv};
    *(float4*)(yp + 48) = float4{O3[0]*inv, O3[1]*inv, O3[2]*inv, O3[3]*inv};
  }
}

// ---------------------------------------------------------------------------
extern "C" void kernel_launch(void* const* d_in, const int* in_sizes, int n_in,
                              void* d_out, int out_size, void* d_ws, size_t ws_size,
                              hipStream_t stream)
{
  const float* x     = (const float*)d_in[0];
  const float* W_dq  = (const float*)d_in[1];
  const float* W_uq  = (const float*)d_in[2];
  const float* W_dkv = (const float*)d_in[3];
  const float* W_uk  = (const float*)d_in[4];
  const float* W_uv  = (const float*)d_in[5];
  const float* W_o   = (const float*)d_in[6];

  float* y_out   = (float*)d_out;
  float* ckv_out = y_out + (long)kB * kT * kC;

  // workspace layout (~52 MB)
  char* ws = (char*)d_ws;
  bf16* xb      = (bf16*)(ws + 0);           //  8 MB
  bf16* qfullb  = (bf16*)(ws + 8388608);     //  8 MB
  bf16* q_lowb  = (bf16*)(ws + 16777216);    //  4 MB
  bf16* ckv_b   = (bf16*)(ws + 20971520);    //  4 MB
  bf16* K_head  = (bf16*)(ws + 25165824);    //  8 MB (B,NH,T,64)
  bf16* V_headT = (bf16*)(ws + 33554432);    //  8 MB (B,NH,64,T)
  bf16* W_dqb   = (bf16*)(ws + 41943040);    //  1 MB
  bf16* W_uqb   = (bf16*)(ws + 42991616);    //  1 MB
  bf16* W_dkvb  = (bf16*)(ws + 44040192);    //  1 MB
  bf16* W_ob    = (bf16*)(ws + 45088768);    //  2 MB
  bf16* W_uqTb  = (bf16*)(ws + 47185920);    //  1 MB
  bf16* W_ukTb  = (bf16*)(ws + 48234496);    //  1 MB
  bf16* W_uvTb  = (bf16*)(ws + 49283072);    //  1 MB
  bf16* W_dqTb  = (bf16*)(ws + 50331648);    //  1 MB
  bf16* tmpT    = (bf16*)(ws + 51380224);    // 0.5 MB
  bf16* k_effF  = (bf16*)(ws + 51904512);    //  1 MB (1024 c x 512 l)
  bf16* v_effT  = (bf16*)(ws + 52953088);    //  1 MB (1024 j x 512 l)

  const dim3 blk(256);
  const long TL = (long)kT * kL;
  const float kScale = 0.125f * 1.44269504088896f;   // 1/sqrt(64) * log2(e)

  casts_all<<<dim3(6656), blk, 0, stream>>>(
      x, W_dq, W_uq, W_dkv, W_o, xb, W_dqb, W_uqb, W_dkvb, W_ob);
  tcasts_all<<<dim3(32, 32, 4), blk, 0, stream>>>(
      W_uq, W_uk, W_uv, W_dq, W_uqTb, W_ukTb, W_uvTb, W_dqTb);

  // tmpT[l][q] = (W_uk^T W_uq)[l][q]
  mm_nt<bf16><<<dim3(8, 8, 1), blk, 0, stream>>>(
      W_ukTb, 1024, 0, 0, W_uqTb, 1024, 0, 0, tmpT, 512, 0, 0, 1024, 1.0f);
  // k_effF[c][l] = (W_dq^T W_uq^T W_uk)[c][l]
  mm_nt<bf16><<<dim3(16, 8, 1), blk, 0, stream>>>(
      W_dqTb, 512, 0, 0, tmpT, 512, 0, 0, k_effF, 512, 0, 0, 512, 1.0f);
  // v_effT[j][l] = (W_uv^T W_o^T)^T[j][l]
  mm_nt<bf16><<<dim3(16, 8, 1), blk, 0, stream>>>(
      W_ob, 1024, 0, 0, W_uvTb, 1024, 0, 0, v_effT, 512, 0, 0, 1024, 1.0f);
  // q_low = x @ W_dq^T ; qfull = q_low @ W_uq^T
  mm_nt<bf16><<<dim3(64, 8, 1), blk, 0, stream>>>(
      xb, 1024, 0, 0, W_dqb, 1024, 0, 0, q_lowb, 512, 0, 0, 1024, 1.0f);
  mm_nt<bf16><<<dim3(64, 16, 1), blk, 0, stream>>>(
      q_lowb, 512, 0, 0, W_uqb, 512, 0, 0, qfullb, 1024, 0, 0, 512, 1.0f);
  // c_kv = x @ W_dkv^T (bf16)
  mm_nt<bf16><<<dim3(64, 8, 1), blk, 0, stream>>>(
      xb, 1024, 0, 0, W_dkvb, 1024, 0, 0, ckv_b, 512, 0, 0, 1024, 1.0f);
  // K_head[b,h][t][d] = kScale * sum_l ckv[b][t][l] * k_effF[h*64+d][l]
  mm_nt<bf16><<<dim3(32, 1, 32), blk, 0, stream>>>(
      ckv_b, 512, TL, 0,
      k_effF, 512, 0, (long)64 * 512,
      K_head, 64, (long)kNH * kT * 64, (long)kT * 64,
      512, kScale);
  // V_headT[b,h][d][t] = sum_l v_effT[h*64+d][l] * ckv[b][t][l]
  mm_nt<bf16><<<dim3(1, 32, 32), blk, 0, stream>>>(
      v_effT, 512, 0, (long)64 * 512,
      ckv_b, 512, TL, 0,
      V_headT, kT, (long)kNH * 64 * kT, (long)64 * kT,
      512, 1.0f);
  // flash: y fp32 direct, balanced 1D grid
  flash64<<<dim3(512), dim3(512), 0, stream>>>(
      qfullb, K_head, V_headT, y_out);
  // FINAL kernel: write the fp32 c_kv output tail last.
  upcast_kernel<<<dim3(2048), blk, 0, stream>>>(ckv_b, ckv_out, 2097152);

  (void)in_sizes; (void)n_in; (void)out_size; (void)ws_size;
}